// Round 2
// baseline (18946.111 us; speedup 1.0000x reference)
//
#include <hip/hip_runtime.h>

// Seq2Seq GRU + Bahdanau attention, fp32.
// B=32 S=64 T=48 E=512 H=1024 V=32000.
// R2: persistent encoder/decoder kernels with device-scope grid barrier
// replace ~205 tiny per-step launches. Logits GEMM still fp32 k_gemm.

#define BB 32
#define SS 64
#define TT 48
#define TD 47
#define EE 512
#define HH 1024
#define GG 3072
#define VV 32000
#define SOS_IDX 1
#define NBLK 256
#define NTHR 512

static __device__ __forceinline__ float sigmoid_f(float x) {
    return 1.0f / (1.0f + __expf(-x));
}
static __device__ __forceinline__ float tanh_f(float x) {
    return 1.0f - 2.0f / (__expf(2.0f * x) + 1.0f);
}

// Grid barrier: sense via generation counter. bar[0]=count, bar[1]=gen.
// Device-scope atomics + __threadfence (emits L2 writeback/inv on CDNA) so
// cross-XCD visibility holds. Reset to 0 by hipMemsetAsync each launch.
static __device__ __forceinline__ void gbar(int* bar) {
    __syncthreads();
    if (threadIdx.x == 0) {
        __threadfence();
        int* cnt = bar;
        int* gen = bar + 1;
        int g = __hip_atomic_load(gen, __ATOMIC_RELAXED, __HIP_MEMORY_SCOPE_AGENT);
        int v = __hip_atomic_fetch_add(cnt, 1, __ATOMIC_ACQ_REL, __HIP_MEMORY_SCOPE_AGENT);
        if (v == NBLK - 1) {
            __hip_atomic_store(cnt, 0, __ATOMIC_RELAXED, __HIP_MEMORY_SCOPE_AGENT);
            __hip_atomic_store(gen, g + 1, __ATOMIC_RELEASE, __HIP_MEMORY_SCOPE_AGENT);
        } else {
            while (__hip_atomic_load(gen, __ATOMIC_ACQUIRE, __HIP_MEMORY_SCOPE_AGENT) == g) {
                __builtin_amdgcn_s_sleep(1);
            }
        }
        __threadfence();
    }
    __syncthreads();
}

__global__ void k_dec_idx(const int* __restrict__ tgt, int* __restrict__ idx) {
    int m = blockIdx.x * 256 + threadIdx.x;
    if (m < TD * BB) {
        int t = m >> 5, b = m & 31;
        idx[m] = (t == 0) ? SOS_IDX : tgt[b * TT + t];
    }
}

// C[m,n] = sum_k A[row(m),k] * Wt[n,k] + bias[n]
__global__ __launch_bounds__(256) void k_gemm(
    const float* __restrict__ A, const float* __restrict__ Wt,
    const float* __restrict__ bias, float* __restrict__ C,
    const int* __restrict__ rowidx,
    int M, int N, int K, int lda, int ldw, int ldc, int permute)
{
    __shared__ __align__(16) float As[16][64];
    __shared__ __align__(16) float Bs[16][64];
    const int tid = threadIdx.x;
    const int tm = tid >> 4;
    const int tn = tid & 15;
    const int row0 = blockIdx.y * 64;
    const int col0 = blockIdx.x * 64;
    const int lr = tid >> 2;
    const int lq = tid & 3;

    long arow_off = -1;
    {
        int arow = row0 + lr;
        if (arow < M) {
            int r = rowidx ? rowidx[arow] : arow;
            arow_off = (long)r * lda;
        }
    }
    long wrow_off = -1;
    {
        int wcol = col0 + lr;
        if (wcol < N) wrow_off = (long)wcol * ldw;
    }

    float acc[4][4];
#pragma unroll
    for (int i = 0; i < 4; ++i)
#pragma unroll
        for (int j = 0; j < 4; ++j) acc[i][j] = 0.f;

    for (int k0 = 0; k0 < K; k0 += 16) {
        float4 av = make_float4(0.f, 0.f, 0.f, 0.f);
        if (arow_off >= 0) av = *(const float4*)(A + arow_off + k0 + lq * 4);
        float4 wv = make_float4(0.f, 0.f, 0.f, 0.f);
        if (wrow_off >= 0) wv = *(const float4*)(Wt + wrow_off + k0 + lq * 4);
        __syncthreads();
        As[lq * 4 + 0][lr] = av.x; As[lq * 4 + 1][lr] = av.y;
        As[lq * 4 + 2][lr] = av.z; As[lq * 4 + 3][lr] = av.w;
        Bs[lq * 4 + 0][lr] = wv.x; Bs[lq * 4 + 1][lr] = wv.y;
        Bs[lq * 4 + 2][lr] = wv.z; Bs[lq * 4 + 3][lr] = wv.w;
        __syncthreads();
#pragma unroll
        for (int kk = 0; kk < 16; ++kk) {
            float4 a4 = *(const float4*)&As[kk][tm * 4];
            float4 b4 = *(const float4*)&Bs[kk][tn * 4];
            acc[0][0] += a4.x * b4.x; acc[0][1] += a4.x * b4.y;
            acc[0][2] += a4.x * b4.z; acc[0][3] += a4.x * b4.w;
            acc[1][0] += a4.y * b4.x; acc[1][1] += a4.y * b4.y;
            acc[1][2] += a4.y * b4.z; acc[1][3] += a4.y * b4.w;
            acc[2][0] += a4.z * b4.x; acc[2][1] += a4.z * b4.y;
            acc[2][2] += a4.z * b4.z; acc[2][3] += a4.z * b4.w;
            acc[3][0] += a4.w * b4.x; acc[3][1] += a4.w * b4.y;
            acc[3][2] += a4.w * b4.z; acc[3][3] += a4.w * b4.w;
        }
    }

    float4 bv = make_float4(0.f, 0.f, 0.f, 0.f);
    if (bias) bv = *(const float4*)(bias + col0 + tn * 4);
#pragma unroll
    for (int i = 0; i < 4; ++i) {
        int m = row0 + tm * 4 + i;
        if (m >= M) continue;
        int orow = permute ? ((m & 31) * TD + (m >> 5)) : m;
        float4 v;
        v.x = acc[i][0] + bv.x; v.y = acc[i][1] + bv.y;
        v.z = acc[i][2] + bv.z; v.w = acc[i][3] + bv.w;
        *(float4*)(C + (long)orow * ldc + col0 + tn * 4) = v;
    }
}

// ---------------- persistent encoder ----------------
// hT4 layout: element (k,b) at (k>>2)*128 + b*4 + (k&3).
// 256 blocks x 512 threads. Block owns j0..j0+3. Thread = (b, ks); ks=k/64.
__global__ __launch_bounds__(NTHR, 2) void p_enc(
    const float* __restrict__ gi, const float* __restrict__ Whh,
    const float* __restrict__ bhh, float* hA, float* hB,
    float* __restrict__ enc_out, int* bar)
{
    const int tid = threadIdx.x, bid = blockIdx.x;
    const int b = tid & 31, ks = tid >> 5;      // ks 0..15
    const int j0 = bid * 4;
    const int kc = ks * 64;
    __shared__ float red[3][4][16][32];

    for (int i = bid * NTHR + tid; i < BB * HH; i += NBLK * NTHR) hA[i] = 0.f;
    gbar(bar);

    const float* wp[12];
#pragma unroll
    for (int g = 0; g < 3; ++g)
#pragma unroll
        for (int jj = 0; jj < 4; ++jj)
            wp[g * 4 + jj] = Whh + ((long)((g << 10) + j0 + jj) << 10) + kc;

    float* cur = hA;
    float* nxt = hB;
    for (int s = 0; s < SS; ++s) {
        float acc[12];
#pragma unroll
        for (int u = 0; u < 12; ++u) acc[u] = 0.f;
        const float* hb = cur + ks * 2048 + b * 4;
        for (int i = 0; i < 16; ++i) {
            float4 h4 = *(const float4*)(hb + (i << 7));
#pragma unroll
            for (int u = 0; u < 12; ++u) {
                float4 w4 = *(const float4*)(wp[u] + (i << 2));
                acc[u] += h4.x * w4.x + h4.y * w4.y + h4.z * w4.z + h4.w * w4.w;
            }
        }
#pragma unroll
        for (int g = 0; g < 3; ++g)
#pragma unroll
            for (int jj = 0; jj < 4; ++jj) red[g][jj][ks][b] = acc[g * 4 + jj];
        __syncthreads();
        if (tid < 128) {
            const int jj = tid >> 5, fb = tid & 31, j = j0 + jj;
            float s0 = 0.f, s1 = 0.f, s2 = 0.f;
#pragma unroll
            for (int q = 0; q < 16; ++q) {
                s0 += red[0][jj][q][fb];
                s1 += red[1][jj][q][fb];
                s2 += red[2][jj][q][fb];
            }
            const float* gr = gi + ((long)(fb * SS + s)) * GG;
            float r = sigmoid_f(gr[j] + s0 + bhh[j]);
            float z = sigmoid_f(gr[HH + j] + s1 + bhh[HH + j]);
            float n = tanh_f(gr[2 * HH + j] + r * (s2 + bhh[2 * HH + j]));
            float hold = cur[((j >> 2) << 7) + (fb << 2) + (j & 3)];
            float hnew = (1.f - z) * n + z * hold;
            nxt[((j >> 2) << 7) + (fb << 2) + (j & 3)] = hnew;
            enc_out[((long)(fb * SS + s)) * HH + j] = hnew;
        }
        gbar(bar);
        float* t2 = cur; cur = nxt; nxt = t2;
    }
}

// ---------------- persistent decoder ----------------
__global__ __launch_bounds__(NTHR, 2) void p_dec(
    const float* __restrict__ gi, const float* __restrict__ Whh,
    const float* __restrict__ bhh, const float* __restrict__ Wih,
    const float* __restrict__ wq, const float* __restrict__ bq,
    const float* __restrict__ keys, const float* __restrict__ wsv,
    const float* __restrict__ bsv, const int* __restrict__ src,
    const float* __restrict__ enc_out, float* hA, float* hB,
    float* __restrict__ qrow, float* __restrict__ ctxT4,
    float* __restrict__ h2all, float* __restrict__ attn_out, int* bar)
{
    const int tid = threadIdx.x, bid = blockIdx.x;
    const int b = tid & 31, ks = tid >> 5;
    const int j0 = bid * 4;
    const int kc = ks * 64;
    __shared__ float redA[4][16][32];
    __shared__ float redC[6][4][16][32];
    __shared__ float qs[HH];
    __shared__ float wss[HH];
    __shared__ float sc[8][64];
    __shared__ float wl[64];

    const float* wqp[4];
    const float* whp[12];
    const float* wxp[12];
#pragma unroll
    for (int jj = 0; jj < 4; ++jj)
        wqp[jj] = wq + ((long)(j0 + jj) << 10) + kc;
#pragma unroll
    for (int g = 0; g < 3; ++g)
#pragma unroll
        for (int jj = 0; jj < 4; ++jj) {
            whp[g * 4 + jj] = Whh + ((long)((g << 10) + j0 + jj) << 10) + kc;
            wxp[g * 4 + jj] = Wih + (long)((g << 10) + j0 + jj) * (EE + HH) + EE + kc;
        }

    for (int i = tid; i < HH; i += NTHR) wss[i] = wsv[i];

    float* cur = hA;
    float* nxt = hB;
    for (int t = 0; t < TD; ++t) {
        // ---- phase A: q = h @ wq^T + bq
        {
            float acc[4] = {0.f, 0.f, 0.f, 0.f};
            const float* hb = cur + ks * 2048 + b * 4;
            for (int i = 0; i < 16; ++i) {
                float4 h4 = *(const float4*)(hb + (i << 7));
#pragma unroll
                for (int u = 0; u < 4; ++u) {
                    float4 w4 = *(const float4*)(wqp[u] + (i << 2));
                    acc[u] += h4.x * w4.x + h4.y * w4.y + h4.z * w4.z + h4.w * w4.w;
                }
            }
#pragma unroll
            for (int u = 0; u < 4; ++u) redA[u][ks][b] = acc[u];
            __syncthreads();
            if (tid < 128) {
                int jj = tid >> 5, fb = tid & 31, j = j0 + jj;
                float sum = 0.f;
#pragma unroll
                for (int q = 0; q < 16; ++q) sum += redA[jj][q][fb];
                qrow[fb * HH + j] = sum + bq[j];
            }
        }
        gbar(bar);
        // ---- phase B: attention (blocks 0..31, block = batch elem)
        if (bid < BB) {
            const int ab = bid;
            for (int i = tid; i < HH; i += NTHR) qs[i] = qrow[ab * HH + i];
            __syncthreads();
            {
                const int s4 = tid >> 3, kq = tid & 7;     // s4 0..63, 128-k chunk
                const float* kr = keys + ((long)(ab * SS + s4)) * HH + kq * 128;
                float acc = 0.f;
                for (int i = 0; i < 32; ++i) {
                    float4 kv = *(const float4*)(kr + (i << 2));
                    int k = kq * 128 + (i << 2);
                    acc += tanh_f(qs[k] + kv.x) * wss[k]
                         + tanh_f(qs[k + 1] + kv.y) * wss[k + 1]
                         + tanh_f(qs[k + 2] + kv.z) * wss[k + 2]
                         + tanh_f(qs[k + 3] + kv.w) * wss[k + 3];
                }
                sc[kq][s4] = acc;
            }
            __syncthreads();
            if (tid < 64) {
                float v = bsv[0];
#pragma unroll
                for (int q = 0; q < 8; ++q) v += sc[q][tid];
                bool valid = src[ab * SS + tid] != 0;
                float m = valid ? v : -3.0e38f;
                for (int off = 32; off; off >>= 1) m = fmaxf(m, __shfl_xor(m, off));
                float e = valid ? __expf(v - m) : 0.f;
                float ssum = e;
                for (int off = 32; off; off >>= 1) ssum += __shfl_xor(ssum, off);
                float wgt = e / ssum;
                wl[tid] = wgt;
                attn_out[((long)ab * TD + t) * SS + tid] = wgt;
            }
            __syncthreads();
            if (tid < 256) {
                float4 a = make_float4(0.f, 0.f, 0.f, 0.f);
                const float* er = enc_out + (long)ab * SS * HH + tid * 4;
                for (int s2 = 0; s2 < SS; ++s2) {
                    float wgt = wl[s2];
                    float4 ev = *(const float4*)(er + ((long)s2 << 10));
                    a.x += wgt * ev.x; a.y += wgt * ev.y;
                    a.z += wgt * ev.z; a.w += wgt * ev.w;
                }
                *(float4*)(ctxT4 + (tid << 7) + (ab << 2)) = a;
            }
        }
        gbar(bar);
        // ---- phase C: GRU update (h side + ctx side kept separate for gate n)
        {
            float ah[12], ax[12];
#pragma unroll
            for (int u = 0; u < 12; ++u) { ah[u] = 0.f; ax[u] = 0.f; }
            const float* hb = cur + ks * 2048 + b * 4;
            const float* cb = ctxT4 + ks * 2048 + b * 4;
            for (int i = 0; i < 16; ++i) {
                float4 h4 = *(const float4*)(hb + (i << 7));
#pragma unroll
                for (int u = 0; u < 12; ++u) {
                    float4 w4 = *(const float4*)(whp[u] + (i << 2));
                    ah[u] += h4.x * w4.x + h4.y * w4.y + h4.z * w4.z + h4.w * w4.w;
                }
            }
            for (int i = 0; i < 16; ++i) {
                float4 c4 = *(const float4*)(cb + (i << 7));
#pragma unroll
                for (int u = 0; u < 12; ++u) {
                    float4 w4 = *(const float4*)(wxp[u] + (i << 2));
                    ax[u] += c4.x * w4.x + c4.y * w4.y + c4.z * w4.z + c4.w * w4.w;
                }
            }
#pragma unroll
            for (int g = 0; g < 3; ++g)
#pragma unroll
                for (int jj = 0; jj < 4; ++jj) {
                    redC[g][jj][ks][b] = ah[g * 4 + jj];
                    redC[3 + g][jj][ks][b] = ax[g * 4 + jj];
                }
            __syncthreads();
            if (tid < 128) {
                int jj = tid >> 5, fb = tid & 31, j = j0 + jj;
                float sh0 = 0.f, sh1 = 0.f, sh2 = 0.f;
                float sx0 = 0.f, sx1 = 0.f, sx2 = 0.f;
#pragma unroll
                for (int q = 0; q < 16; ++q) {
                    sh0 += redC[0][jj][q][fb]; sh1 += redC[1][jj][q][fb]; sh2 += redC[2][jj][q][fb];
                    sx0 += redC[3][jj][q][fb]; sx1 += redC[4][jj][q][fb]; sx2 += redC[5][jj][q][fb];
                }
                const float* gr = gi + ((long)(t * BB + fb)) * GG;
                float r = sigmoid_f(gr[j] + sx0 + sh0 + bhh[j]);
                float z = sigmoid_f(gr[HH + j] + sx1 + sh1 + bhh[HH + j]);
                float n = tanh_f(gr[2 * HH + j] + sx2 + r * (sh2 + bhh[2 * HH + j]));
                float hold = cur[((j >> 2) << 7) + (fb << 2) + (j & 3)];
                float hnew = (1.f - z) * n + z * hold;
                nxt[((j >> 2) << 7) + (fb << 2) + (j & 3)] = hnew;
                h2all[((long)(t * BB + fb)) * HH + j] = hnew;
            }
        }
        gbar(bar);
        float* t2 = cur; cur = nxt; nxt = t2;
    }
}

extern "C" void kernel_launch(void* const* d_in, const int* in_sizes, int n_in,
                              void* d_out, int out_size, void* d_ws, size_t ws_size,
                              hipStream_t stream)
{
    const int*   src  = (const int*)d_in[0];
    const int*   tgt  = (const int*)d_in[1];
    const float* eemb = (const float*)d_in[2];
    const float* ewih = (const float*)d_in[3];
    const float* ewhh = (const float*)d_in[4];
    const float* ebih = (const float*)d_in[5];
    const float* ebhh = (const float*)d_in[6];
    const float* wq   = (const float*)d_in[7];
    const float* bq   = (const float*)d_in[8];
    const float* wk   = (const float*)d_in[9];
    const float* bk   = (const float*)d_in[10];
    const float* wsv  = (const float*)d_in[11];
    const float* bsv  = (const float*)d_in[12];
    const float* demb = (const float*)d_in[13];
    const float* dwih = (const float*)d_in[14];
    const float* dwhh = (const float*)d_in[15];
    const float* dbih = (const float*)d_in[16];
    const float* dbhh = (const float*)d_in[17];
    const float* wo   = (const float*)d_in[18];
    const float* bo   = (const float*)d_in[19];
    float* out = (float*)d_out;

    float* w = (float*)d_ws;
    float* enc_gi  = w;                                // [B*S][3H]
    float* dec_gi  = enc_gi  + (long)BB * SS * GG;     // [TD*B][3H]
    float* enc_out = dec_gi  + (long)TD * BB * GG;     // [B*S][H]
    float* keys    = enc_out + (long)BB * SS * HH;     // [B*S][H]
    float* h2all   = keys    + (long)BB * SS * HH;     // [TD*B][H]
    float* hA      = h2all   + (long)TD * BB * HH;     // hT4
    float* hB      = hA + BB * HH;
    float* qrow    = hB + BB * HH;                     // [B][H]
    float* ctxT4   = qrow + BB * HH;                   // hT4 layout
    int*   didx    = (int*)(ctxT4 + BB * HH);          // [TD*B]
    int*   bar     = didx + TD * BB + 8;               // grid barrier (2 ints)

    float* attn_out = out + (long)BB * TD * VV;

    hipMemsetAsync(bar, 0, 2 * sizeof(int), stream);
    k_dec_idx<<<dim3((TD * BB + 255) / 256), 256, 0, stream>>>(tgt, didx);

    // enc_gi = gather(enc_embed)@enc_w_ih^T + b_ih
    k_gemm<<<dim3(GG / 64, (BB * SS) / 64), 256, 0, stream>>>(
        eemb, ewih, ebih, enc_gi, src, BB * SS, GG, EE, EE, EE, GG, 0);
    // dec_gi = gather(dec_embed)@dec_w_ih[:, :E]^T + b_ih
    k_gemm<<<dim3(GG / 64, (TD * BB + 63) / 64), 256, 0, stream>>>(
        demb, dwih, dbih, dec_gi, didx, TD * BB, GG, EE, EE, EE + HH, GG, 0);

    p_enc<<<dim3(NBLK), dim3(NTHR), 0, stream>>>(
        enc_gi, ewhh, ebhh, hA, hB, enc_out, bar);

    // keys = enc_out @ wk^T + bk
    k_gemm<<<dim3(HH / 64, (BB * SS) / 64), 256, 0, stream>>>(
        enc_out, wk, bk, keys, nullptr, BB * SS, HH, HH, HH, HH, HH, 0);

    p_dec<<<dim3(NBLK), dim3(NTHR), 0, stream>>>(
        dec_gi, dwhh, dbhh, dwih, wq, bq, keys, wsv, bsv, src, enc_out,
        hA, hB, qrow, ctxT4, h2all, attn_out, bar);

    // logits = h2all @ wo^T + bo, rows permuted (t*B+b) -> (b*TD+t)
    k_gemm<<<dim3(VV / 64, (TD * BB + 63) / 64), 256, 0, stream>>>(
        h2all, wo, bo, out, nullptr, TD * BB, VV, HH, HH, HH, VV, 1);
}

// Round 3
// 12458.767 us; speedup vs baseline: 1.5207x; 1.5207x over previous
//
#include <hip/hip_runtime.h>

// Seq2Seq GRU + Bahdanau attention, fp32. B=32 S=64 T=48 E=512 H=1024 V=32000.
// R3: fence-free persistent recurrence. Cross-block data (h, ctx) goes through
// relaxed agent-scope atomics (coherent point = L3, no L2 flush/inv), barrier is
// a monotonic relaxed counter + relaxed spin. L2 stays warm for all weights.

#define BB 32
#define SS 64
#define TT 48
#define TD 47
#define EE 512
#define HH 1024
#define GG 3072
#define VV 32000
#define SOS_IDX 1
#define NBE 128          // encoder blocks
#define NBG 128          // decoder GRU blocks
#define NBA 32           // decoder attention blocks
#define NBD (NBG + NBA)  // decoder total
#define NTHR 512

static __device__ __forceinline__ float sigmoid_f(float x) {
    return 1.0f / (1.0f + __expf(-x));
}
static __device__ __forceinline__ float tanh_f(float x) {
    return 1.0f - 2.0f / (__expf(2.0f * x) + 1.0f);
}

// Coherent (cache-bypassing) accesses for cross-block data. Relaxed: no fences,
// no buffer_inv/wbl2 -> L2 keeps read-only weights warm across barriers.
static __device__ __forceinline__ float cload(const float* p) {
    return __hip_atomic_load(p, __ATOMIC_RELAXED, __HIP_MEMORY_SCOPE_AGENT);
}
static __device__ __forceinline__ void cstore(float* p, float v) {
    __hip_atomic_store(p, v, __ATOMIC_RELAXED, __HIP_MEMORY_SCOPE_AGENT);
}

// Monotonic grid barrier, fence-free. Each block keeps a local step count.
// s_waitcnt drains this wave's coherent stores before arrival is published.
static __device__ __forceinline__ void gbar(int* bar, int nblk, int& bstep) {
    __syncthreads();   // compiler emits s_waitcnt vmcnt(0) lgkmcnt(0) before s_barrier
    bstep += 1;
    if (threadIdx.x == 0) {
        asm volatile("s_waitcnt vmcnt(0) lgkmcnt(0)" ::: "memory");
        int target = bstep * nblk;
        __hip_atomic_fetch_add(bar, 1, __ATOMIC_RELAXED, __HIP_MEMORY_SCOPE_AGENT);
        while (__hip_atomic_load(bar, __ATOMIC_RELAXED, __HIP_MEMORY_SCOPE_AGENT) < target) {
            __builtin_amdgcn_s_sleep(2);
        }
        asm volatile("" ::: "memory");
    }
    __syncthreads();
}

__global__ void k_dec_idx(const int* __restrict__ tgt, int* __restrict__ idx) {
    int m = blockIdx.x * 256 + threadIdx.x;
    if (m < TD * BB) {
        int t = m >> 5, b = m & 31;
        idx[m] = (t == 0) ? SOS_IDX : tgt[b * TT + t];
    }
}

// C[m,n] = sum_k A[row(m),k] * Wt[n,k] + bias[n]
__global__ __launch_bounds__(256) void k_gemm(
    const float* __restrict__ A, const float* __restrict__ Wt,
    const float* __restrict__ bias, float* __restrict__ C,
    const int* __restrict__ rowidx,
    int M, int N, int K, int lda, int ldw, int ldc, int permute)
{
    __shared__ __align__(16) float As[16][64];
    __shared__ __align__(16) float Bs[16][64];
    const int tid = threadIdx.x;
    const int tm = tid >> 4;
    const int tn = tid & 15;
    const int row0 = blockIdx.y * 64;
    const int col0 = blockIdx.x * 64;
    const int lr = tid >> 2;
    const int lq = tid & 3;

    long arow_off = -1;
    {
        int arow = row0 + lr;
        if (arow < M) {
            int r = rowidx ? rowidx[arow] : arow;
            arow_off = (long)r * lda;
        }
    }
    long wrow_off = -1;
    {
        int wcol = col0 + lr;
        if (wcol < N) wrow_off = (long)wcol * ldw;
    }

    float acc[4][4];
#pragma unroll
    for (int i = 0; i < 4; ++i)
#pragma unroll
        for (int j = 0; j < 4; ++j) acc[i][j] = 0.f;

    for (int k0 = 0; k0 < K; k0 += 16) {
        float4 av = make_float4(0.f, 0.f, 0.f, 0.f);
        if (arow_off >= 0) av = *(const float4*)(A + arow_off + k0 + lq * 4);
        float4 wv = make_float4(0.f, 0.f, 0.f, 0.f);
        if (wrow_off >= 0) wv = *(const float4*)(Wt + wrow_off + k0 + lq * 4);
        __syncthreads();
        As[lq * 4 + 0][lr] = av.x; As[lq * 4 + 1][lr] = av.y;
        As[lq * 4 + 2][lr] = av.z; As[lq * 4 + 3][lr] = av.w;
        Bs[lq * 4 + 0][lr] = wv.x; Bs[lq * 4 + 1][lr] = wv.y;
        Bs[lq * 4 + 2][lr] = wv.z; Bs[lq * 4 + 3][lr] = wv.w;
        __syncthreads();
#pragma unroll
        for (int kk = 0; kk < 16; ++kk) {
            float4 a4 = *(const float4*)&As[kk][tm * 4];
            float4 b4 = *(const float4*)&Bs[kk][tn * 4];
            acc[0][0] += a4.x * b4.x; acc[0][1] += a4.x * b4.y;
            acc[0][2] += a4.x * b4.z; acc[0][3] += a4.x * b4.w;
            acc[1][0] += a4.y * b4.x; acc[1][1] += a4.y * b4.y;
            acc[1][2] += a4.y * b4.z; acc[1][3] += a4.y * b4.w;
            acc[2][0] += a4.z * b4.x; acc[2][1] += a4.z * b4.y;
            acc[2][2] += a4.z * b4.z; acc[2][3] += a4.z * b4.w;
            acc[3][0] += a4.w * b4.x; acc[3][1] += a4.w * b4.y;
            acc[3][2] += a4.w * b4.z; acc[3][3] += a4.w * b4.w;
        }
    }

    float4 bv = make_float4(0.f, 0.f, 0.f, 0.f);
    if (bias) bv = *(const float4*)(bias + col0 + tn * 4);
#pragma unroll
    for (int i = 0; i < 4; ++i) {
        int m = row0 + tm * 4 + i;
        if (m >= M) continue;
        int orow = permute ? ((m & 31) * TD + (m >> 5)) : m;
        float4 v;
        v.x = acc[i][0] + bv.x; v.y = acc[i][1] + bv.y;
        v.z = acc[i][2] + bv.z; v.w = acc[i][3] + bv.w;
        *(float4*)(C + (long)orow * ldc + col0 + tn * 4) = v;
    }
}

// ---------------- persistent encoder ----------------
// h layout: [k][b] plain (k*32+b). Block owns 8 j-cols. Thread=(b, ks 0..15).
__global__ __launch_bounds__(NTHR, 1) void p_enc(
    const float* __restrict__ gi, const float* __restrict__ Whh,
    const float* __restrict__ bhh, float* hA, float* hB,
    float* __restrict__ enc_out, int* bar)
{
    __shared__ float red[24][16][32];
    const int tid = threadIdx.x, bid = blockIdx.x;
    const int b = tid & 31, ks = tid >> 5;
    const int j0 = bid * 8;
    const int kc = ks * 64;
    int bstep = 0;

    for (int i = bid * NTHR + tid; i < BB * HH; i += NBE * NTHR)
        cstore(hA + i, 0.f);
    gbar(bar, NBE, bstep);

    const float* wbase = Whh + (size_t)j0 * HH + kc;
    float* cur = hA;
    float* nxt = hB;
    for (int s = 0; s < SS; ++s) {
        float acc[24];
#pragma unroll
        for (int u = 0; u < 24; ++u) acc[u] = 0.f;
        const float* hb = cur + kc * 32 + b;
        for (int i = 0; i < 16; ++i) {
            float h0 = cload(hb + (i * 4 + 0) * 32);
            float h1 = cload(hb + (i * 4 + 1) * 32);
            float h2 = cload(hb + (i * 4 + 2) * 32);
            float h3 = cload(hb + (i * 4 + 3) * 32);
#pragma unroll
            for (int g = 0; g < 3; ++g)
#pragma unroll
                for (int jj = 0; jj < 8; ++jj) {
                    float4 w4 = *(const float4*)(wbase + (((size_t)(g << 10) + jj) << 10) + i * 4);
                    acc[g * 8 + jj] += h0 * w4.x + h1 * w4.y + h2 * w4.z + h3 * w4.w;
                }
        }
#pragma unroll
        for (int u = 0; u < 24; ++u) red[u][ks][b] = acc[u];
        __syncthreads();
        if (tid < 256) {
            const int fj = tid >> 5, fb = tid & 31, j = j0 + fj;
            float s0 = 0.f, s1 = 0.f, s2 = 0.f;
#pragma unroll
            for (int q = 0; q < 16; ++q) {
                s0 += red[fj][q][fb];
                s1 += red[8 + fj][q][fb];
                s2 += red[16 + fj][q][fb];
            }
            const float* gr = gi + (size_t)(fb * SS + s) * GG;
            float r = sigmoid_f(gr[j] + s0 + bhh[j]);
            float z = sigmoid_f(gr[HH + j] + s1 + bhh[HH + j]);
            float n = tanh_f(gr[2 * HH + j] + r * (s2 + bhh[2 * HH + j]));
            float hold = cload(cur + j * 32 + fb);
            float hnew = (1.f - z) * n + z * hold;
            cstore(nxt + j * 32 + fb, hnew);
            enc_out[(size_t)(fb * SS + s) * HH + j] = hnew;
        }
        gbar(bar, NBE, bstep);
        float* tq = cur; cur = nxt; nxt = tq;
    }
}

// ---------------- persistent decoder ----------------
// blocks 0..127: GRU (8 j-cols each). blocks 128..159: attention (1 batch each).
__global__ __launch_bounds__(NTHR, 1) void p_dec(
    const float* __restrict__ gi, const float* __restrict__ Whh,
    const float* __restrict__ bhh, const float* __restrict__ Wih,
    const float* __restrict__ wq, const float* __restrict__ bq,
    const float* __restrict__ keys, const float* __restrict__ wsv,
    const float* __restrict__ bsv, const int* __restrict__ src,
    const float* __restrict__ enc_out, float* hA, float* hB,
    float* __restrict__ ctx, float* __restrict__ h2all,
    float* __restrict__ attn_out, int* bar)
{
    __shared__ float smem[12288];          // GRU: red[24][16][32]; attn: aliased below
    __shared__ float shs[3][8][32];        // GRU: reduced h-side gate sums
    const int tid = threadIdx.x, bid = blockIdx.x;
    const bool isg = bid < NBG;
    int bstep = 0;

    // GRU-role constants
    const int b = tid & 31, ks = tid >> 5;
    const int kc = ks * 64;
    const int j0 = bid * 8;
    const float* whbase = Whh + (size_t)j0 * HH + kc;
    const float* wxbase = Wih + (size_t)j0 * (EE + HH) + EE + kc;
    float (*red)[16][32] = (float(*)[16][32])smem;

    // attention-role aliases
    float* qs  = smem;
    float* hs  = smem + 1024;
    float* wss = smem + 2048;
    float* sc  = smem + 3072;              // [8][64]
    float* wl  = smem + 3584;              // [64]
    const int ab = bid - NBG;
    if (!isg) {
        for (int i = tid; i < HH; i += NTHR) wss[i] = wsv[i];
    }

    float* cur = hA;
    float* nxt = hB;
    for (int t = 0; t < TD; ++t) {
        // ======== phase AB: attention (blocks>=128) || h-side GRU dots (blocks<128)
        if (isg) {
            float ah[24];
#pragma unroll
            for (int u = 0; u < 24; ++u) ah[u] = 0.f;
            const float* hb = cur + kc * 32 + b;
            for (int i = 0; i < 16; ++i) {
                float h0 = cload(hb + (i * 4 + 0) * 32);
                float h1 = cload(hb + (i * 4 + 1) * 32);
                float h2 = cload(hb + (i * 4 + 2) * 32);
                float h3 = cload(hb + (i * 4 + 3) * 32);
#pragma unroll
                for (int g = 0; g < 3; ++g)
#pragma unroll
                    for (int jj = 0; jj < 8; ++jj) {
                        float4 w4 = *(const float4*)(whbase + (((size_t)(g << 10) + jj) << 10) + i * 4);
                        ah[g * 8 + jj] += h0 * w4.x + h1 * w4.y + h2 * w4.z + h3 * w4.w;
                    }
            }
#pragma unroll
            for (int u = 0; u < 24; ++u) red[u][ks][b] = ah[u];
            __syncthreads();
            if (tid < 256) {
                const int fj = tid >> 5, fb = tid & 31;
                float s0 = 0.f, s1 = 0.f, s2 = 0.f;
#pragma unroll
                for (int q = 0; q < 16; ++q) {
                    s0 += red[fj][q][fb];
                    s1 += red[8 + fj][q][fb];
                    s2 += red[16 + fj][q][fb];
                }
                shs[0][fj][fb] = s0; shs[1][fj][fb] = s1; shs[2][fj][fb] = s2;
            }
        } else {
            // ---- q = h_ab @ wq^T + bq (wave-per-row, coalesced weight reads)
            for (int i = tid; i < HH; i += NTHR) hs[i] = cload(cur + i * 32 + ab);
            __syncthreads();
            {
                const int lane = tid & 63, wvi = tid >> 6;
#pragma unroll 2
                for (int j = wvi; j < HH; j += 8) {
                    const float* wr = wq + (size_t)j * HH + lane * 16;
                    float a = 0.f;
#pragma unroll
                    for (int c = 0; c < 4; ++c) {
                        float4 w4 = *(const float4*)(wr + c * 4);
                        float4 h4 = *(const float4*)&hs[lane * 16 + c * 4];
                        a += h4.x * w4.x + h4.y * w4.y + h4.z * w4.z + h4.w * w4.w;
                    }
                    for (int off = 32; off; off >>= 1) a += __shfl_xor(a, off);
                    if (lane == 0) qs[j] = a + bq[j];
                }
            }
            __syncthreads();
            // ---- scores
            {
                const int s4 = tid >> 3, kq = tid & 7;
                const float* kr = keys + (size_t)(ab * SS + s4) * HH + kq * 128;
                float a = 0.f;
                for (int i = 0; i < 32; ++i) {
                    float4 kv = *(const float4*)(kr + i * 4);
                    int k = kq * 128 + i * 4;
                    a += tanh_f(qs[k] + kv.x) * wss[k]
                       + tanh_f(qs[k + 1] + kv.y) * wss[k + 1]
                       + tanh_f(qs[k + 2] + kv.z) * wss[k + 2]
                       + tanh_f(qs[k + 3] + kv.w) * wss[k + 3];
                }
                sc[kq * 64 + s4] = a;
            }
            __syncthreads();
            if (tid < 64) {
                float v = bsv[0];
#pragma unroll
                for (int q = 0; q < 8; ++q) v += sc[q * 64 + tid];
                bool valid = src[ab * SS + tid] != 0;
                float m = valid ? v : -3.0e38f;
                for (int off = 32; off; off >>= 1) m = fmaxf(m, __shfl_xor(m, off));
                float e = valid ? __expf(v - m) : 0.f;
                float ssum = e;
                for (int off = 32; off; off >>= 1) ssum += __shfl_xor(ssum, off);
                float wgt = e / ssum;
                wl[tid] = wgt;
                attn_out[((size_t)ab * TD + t) * SS + tid] = wgt;
            }
            __syncthreads();
            if (tid < 256) {
                float4 a4 = make_float4(0.f, 0.f, 0.f, 0.f);
                const float* er = enc_out + (size_t)ab * SS * HH + tid * 4;
                for (int s2 = 0; s2 < SS; ++s2) {
                    float wgt = wl[s2];
                    float4 ev = *(const float4*)(er + ((size_t)s2 << 10));
                    a4.x += wgt * ev.x; a4.y += wgt * ev.y;
                    a4.z += wgt * ev.z; a4.w += wgt * ev.w;
                }
                cstore(ctx + (tid * 4 + 0) * 32 + ab, a4.x);
                cstore(ctx + (tid * 4 + 1) * 32 + ab, a4.y);
                cstore(ctx + (tid * 4 + 2) * 32 + ab, a4.z);
                cstore(ctx + (tid * 4 + 3) * 32 + ab, a4.w);
            }
        }
        gbar(bar, NBD, bstep);
        // ======== phase C: ctx-side dots + gate finalize (GRU blocks)
        if (isg) {
            float ax[24];
#pragma unroll
            for (int u = 0; u < 24; ++u) ax[u] = 0.f;
            const float* cb = ctx + kc * 32 + b;
            for (int i = 0; i < 16; ++i) {
                float c0 = cload(cb + (i * 4 + 0) * 32);
                float c1 = cload(cb + (i * 4 + 1) * 32);
                float c2 = cload(cb + (i * 4 + 2) * 32);
                float c3 = cload(cb + (i * 4 + 3) * 32);
#pragma unroll
                for (int g = 0; g < 3; ++g)
#pragma unroll
                    for (int jj = 0; jj < 8; ++jj) {
                        float4 w4 = *(const float4*)(wxbase + (size_t)((g << 10) + jj) * (EE + HH) + i * 4);
                        ax[g * 8 + jj] += c0 * w4.x + c1 * w4.y + c2 * w4.z + c3 * w4.w;
                    }
            }
            __syncthreads();  // red reuse: prior phase's reads done
#pragma unroll
            for (int u = 0; u < 24; ++u) red[u][ks][b] = ax[u];
            __syncthreads();
            if (tid < 256) {
                const int fj = tid >> 5, fb = tid & 31, j = j0 + fj;
                float sx0 = 0.f, sx1 = 0.f, sx2 = 0.f;
#pragma unroll
                for (int q = 0; q < 16; ++q) {
                    sx0 += red[fj][q][fb];
                    sx1 += red[8 + fj][q][fb];
                    sx2 += red[16 + fj][q][fb];
                }
                float sh0 = shs[0][fj][fb], sh1 = shs[1][fj][fb], sh2 = shs[2][fj][fb];
                const float* gr = gi + (size_t)(t * BB + fb) * GG;
                float r = sigmoid_f(gr[j] + sx0 + sh0 + bhh[j]);
                float z = sigmoid_f(gr[HH + j] + sx1 + sh1 + bhh[HH + j]);
                float n = tanh_f(gr[2 * HH + j] + sx2 + r * (sh2 + bhh[2 * HH + j]));
                float hold = cload(cur + j * 32 + fb);
                float hnew = (1.f - z) * n + z * hold;
                cstore(nxt + j * 32 + fb, hnew);
                h2all[(size_t)(t * BB + fb) * HH + j] = hnew;
            }
        }
        gbar(bar, NBD, bstep);
        float* tq = cur; cur = nxt; nxt = tq;
    }
}

extern "C" void kernel_launch(void* const* d_in, const int* in_sizes, int n_in,
                              void* d_out, int out_size, void* d_ws, size_t ws_size,
                              hipStream_t stream)
{
    const int*   src  = (const int*)d_in[0];
    const int*   tgt  = (const int*)d_in[1];
    const float* eemb = (const float*)d_in[2];
    const float* ewih = (const float*)d_in[3];
    const float* ewhh = (const float*)d_in[4];
    const float* ebih = (const float*)d_in[5];
    const float* ebhh = (const float*)d_in[6];
    const float* wq   = (const float*)d_in[7];
    const float* bq   = (const float*)d_in[8];
    const float* wk   = (const float*)d_in[9];
    const float* bk   = (const float*)d_in[10];
    const float* wsv  = (const float*)d_in[11];
    const float* bsv  = (const float*)d_in[12];
    const float* demb = (const float*)d_in[13];
    const float* dwih = (const float*)d_in[14];
    const float* dwhh = (const float*)d_in[15];
    const float* dbih = (const float*)d_in[16];
    const float* dbhh = (const float*)d_in[17];
    const float* wo   = (const float*)d_in[18];
    const float* bo   = (const float*)d_in[19];
    float* out = (float*)d_out;

    float* w = (float*)d_ws;
    float* enc_gi  = w;                                // [B*S][3H]
    float* dec_gi  = enc_gi  + (size_t)BB * SS * GG;   // [TD*B][3H]
    float* enc_out = dec_gi  + (size_t)TD * BB * GG;   // [B*S][H]
    float* keys    = enc_out + (size_t)BB * SS * HH;   // [B*S][H]
    float* h2all   = keys    + (size_t)BB * SS * HH;   // [TD*B][H]
    float* hA      = h2all   + (size_t)TD * BB * HH;   // [k][b]
    float* hB      = hA + BB * HH;
    float* ctx     = hB + BB * HH;                     // [k][b]
    int*   didx    = (int*)(ctx + BB * HH);            // [TD*B]
    int*   barE    = didx + TD * BB + 64;
    int*   barD    = barE + 64;

    float* attn_out = out + (size_t)BB * TD * VV;

    hipMemsetAsync(barE, 0, 512, stream);
    k_dec_idx<<<dim3((TD * BB + 255) / 256), 256, 0, stream>>>(tgt, didx);

    // enc_gi = gather(enc_embed)@enc_w_ih^T + b_ih
    k_gemm<<<dim3(GG / 64, (BB * SS) / 64), 256, 0, stream>>>(
        eemb, ewih, ebih, enc_gi, src, BB * SS, GG, EE, EE, EE, GG, 0);
    // dec_gi = gather(dec_embed)@dec_w_ih[:, :E]^T + b_ih
    k_gemm<<<dim3(GG / 64, (TD * BB + 63) / 64), 256, 0, stream>>>(
        demb, dwih, dbih, dec_gi, didx, TD * BB, GG, EE, EE, EE + HH, GG, 0);

    p_enc<<<dim3(NBE), dim3(NTHR), 0, stream>>>(
        enc_gi, ewhh, ebhh, hA, hB, enc_out, barE);

    // keys = enc_out @ wk^T + bk
    k_gemm<<<dim3(HH / 64, (BB * SS) / 64), 256, 0, stream>>>(
        enc_out, wk, bk, keys, nullptr, BB * SS, HH, HH, HH, HH, HH, 0);

    p_dec<<<dim3(NBD), dim3(NTHR), 0, stream>>>(
        dec_gi, dwhh, dbhh, dwih, wq, bq, keys, wsv, bsv, src, enc_out,
        hA, hB, ctx, h2all, attn_out, barD);

    // logits = h2all @ wo^T + bo, rows permuted (t*B+b) -> (b*TD+t)
    k_gemm<<<dim3(VV / 64, (TD * BB + 63) / 64), 256, 0, stream>>>(
        h2all, wo, bo, out, nullptr, TD * BB, VV, HH, HH, HH, VV, 1);
}